// Round 17
// baseline (52.500 us; speedup 1.0000x reference)
//
#include <hip/hip_runtime.h>

#define NB   4
#define SEQ  4096
#define CIN  128
#define C4D  32
#define OUTC 128
#define LOG2E 1.44269504f

typedef __attribute__((ext_vector_type(8))) short bf16x8;
typedef __attribute__((ext_vector_type(4))) float f32x4;

__device__ __forceinline__ short f2bf(float f) {
  union { float f; unsigned u; } v; v.f = f;
  unsigned r = v.u + 0x7FFFu + ((v.u >> 16) & 1u);
  return (short)(r >> 16);
}

__device__ __forceinline__ unsigned cvt_pk_bf16(float lo, float hi) {
  unsigned r;
  asm("v_cvt_pk_bf16_f32 %0, %1, %2" : "=v"(r) : "v"(lo), "v"(hi));
  return r;
}

// native 2^x (v_exp_f32) — exp2f() without fast-math lowers to slow OCML.
__device__ __forceinline__ float fast_exp2(float x) {
  float r;
  asm("v_exp_f32 %0, %1" : "=v"(r) : "v"(x));
  return r;
}

__device__ __forceinline__ f32x4 mfma16(bf16x8 a, bf16x8 b, f32x4 c) {
  return __builtin_amdgcn_mfma_f32_16x16x32_bf16(a, b, c, 0, 0, 0);
}

// ---------------------------------------------------------------------------
// Kernel 1: fold value-path weights (unchanged).
// ---------------------------------------------------------------------------
__global__ void k_fuse(const float* __restrict__ wq, const float* __restrict__ wk,
                       const float* __restrict__ wv, const float* __restrict__ weight,
                       const float* __restrict__ bv,
                       short* __restrict__ wqb, short* __restrict__ wkb,
                       short* __restrict__ wfT, float* __restrict__ bfu) {
  int u = blockIdx.x, c = threadIdx.x;
  float a0 = 0.f, a1 = 0.f, a2 = 0.f, a3 = 0.f;
  for (int o = 0; o < OUTC; o += 4) {
    a0 += wv[(o + 0) * CIN + c] * weight[(o + 0) * OUTC + u];
    a1 += wv[(o + 1) * CIN + c] * weight[(o + 1) * OUTC + u];
    a2 += wv[(o + 2) * CIN + c] * weight[(o + 2) * OUTC + u];
    a3 += wv[(o + 3) * CIN + c] * weight[(o + 3) * OUTC + u];
  }
  wfT[u * CIN + c] = f2bf((a0 + a1) + (a2 + a3));
  if (u < C4D) {
    wqb[u * CIN + c] = f2bf(wq[u * CIN + c]);
    wkb[u * CIN + c] = f2bf(wk[u * CIN + c]);
  }
  if (c == 0) {
    float b0 = 0.f, b1 = 0.f;
    for (int o = 0; o < OUTC; o += 2) {
      b0 += bv[o] * weight[o * OUTC + u];
      b1 += bv[o + 1] * weight[(o + 1) * OUTC + u];
    }
    bfu[u] = b0 + b1;
  }
}

// ---------------------------------------------------------------------------
// Kernel 2: projections (unchanged). LDS-swizzled weights, K pre-scaled by
// log2(e), fragment-linear QL/VF outputs.
// ---------------------------------------------------------------------------
__device__ __forceinline__ int wswz(int byte) {
  return byte ^ (((byte >> 8) & 7) << 4);
}

__global__ __launch_bounds__(256) void k_proj(
    const float* __restrict__ x, const float* __restrict__ bq, const float* __restrict__ bk,
    const short* __restrict__ wall, const float* __restrict__ bfu,
    short* __restrict__ ql, short* __restrict__ kb, short* __restrict__ vfb) {
  const int tid = threadIdx.x;
  const int wid = tid >> 6, lane = tid & 63;
  const int lo = lane & 15, g = lane >> 4;
  const int p0 = blockIdx.x * 64 + wid * 16;

  __shared__ __align__(16) short WL[24576];   // 48KB swizzled weights
#pragma unroll
  for (int i = 0; i < 12; ++i) {
    bf16x8 v = *(const bf16x8*)(wall + i * 2048 + tid * 8);
    *(bf16x8*)((char*)WL + wswz((i * 2048 + tid * 8) * 2)) = v;
  }
  __syncthreads();

  auto wfrag = [&](int idx) -> bf16x8 {
    return *(const bf16x8*)((char*)WL + wswz(idx * 2));
  };

  f32x4 aq[2] = {}, ak[2] = {}, as_[8] = {};

#pragma unroll
  for (int kk = 0; kk < 4; ++kk) {
    const float* xp = x + (size_t)(p0 + lo) * CIN + kk * 32 + g * 8;
    float4 xa = *(const float4*)xp;
    float4 xb = *(const float4*)(xp + 4);
    bf16x8 af;
    af[0] = f2bf(xa.x); af[1] = f2bf(xa.y); af[2] = f2bf(xa.z); af[3] = f2bf(xa.w);
    af[4] = f2bf(xb.x); af[5] = f2bf(xb.y); af[6] = f2bf(xb.z); af[7] = f2bf(xb.w);
#pragma unroll
    for (int n = 0; n < 2; ++n) {
      bf16x8 bq_ = wfrag((n * 16 + lo) * CIN + kk * 32 + g * 8);
      aq[n] = mfma16(af, bq_, aq[n]);
      bf16x8 bk_ = wfrag(4096 + (n * 16 + lo) * CIN + kk * 32 + g * 8);
      ak[n] = mfma16(af, bk_, ak[n]);
    }
#pragma unroll
    for (int n = 0; n < 8; ++n) {
      bf16x8 bs = wfrag(8192 + (n * 16 + lo) * CIN + kk * 32 + g * 8);
      as_[n] = mfma16(af, bs, as_[n]);
    }
  }

#pragma unroll
  for (int n = 0; n < 2; ++n) {
    float bqv = bq[n * 16 + lo], bkv = bk[n * 16 + lo];
    int u = n * 16 + lo;
#pragma unroll
    for (int r = 0; r < 4; ++r) {
      int p = p0 + 4 * g + r;
      int bb = p >> 12, s = p & (SEQ - 1);
      ql[(size_t)bb * (SEQ * 32) + (size_t)(s >> 5) * 1024 + ((s >> 4) & 1) * 512 +
         (u >> 3) * 128 + (s & 15) * 8 + (u & 7)] = f2bf(aq[n][r] + bqv);
      kb[(size_t)p * C4D + u] = f2bf((ak[n][r] + bkv) * LOG2E);
    }
  }
  {
    const int p = p0 + 4 * g;          // r = 0; r=0..3 contiguous in VF
    const int bb = p >> 12, s = p & (SEQ - 1);
#pragma unroll
    for (int n = 0; n < 8; ++n) {
      int u = n * 16 + lo;
      float bvv = bfu[u];
      uint2 w;
      w.x = cvt_pk_bf16(as_[n][0] + bvv, as_[n][1] + bvv);
      w.y = cvt_pk_bf16(as_[n][2] + bvv, as_[n][3] + bvv);
      *(uint2*)&vfb[(size_t)bb * (SEQ * 128) + (size_t)(s >> 5) * 4096 + (u >> 4) * 512 +
                    ((s >> 2) & 3) * 128 + (u & 15) * 8 + ((s >> 4) & 1) * 4] = w;
    }
  }
}

// ---------------------------------------------------------------------------
// Kernel 3 (Design III-b, 6-wave j-split => 3 waves/SIMD): wave = 32 i-rows,
// block = 6 waves / 384 thr, j-split 6 (waves get 22/22/21/21/21/21 of the
// 128 j-tiles; wave-uniform bounds). Frozen-max (tile-0 peeled), branch-free
// main loop, l via ones-MFMA, V loads in 2x4-fragment batches to cut peak
// register liveness (target <=170 unified for 3 waves/SIMD). 3-slot LDS
// merge tree. XCD-swizzled blockIdx.
// ---------------------------------------------------------------------------
__global__ __launch_bounds__(384, 3) void k_attn(
    const short* __restrict__ ql, const short* __restrict__ kb,
    const short* __restrict__ vfb, const float* __restrict__ bias,
    float* __restrict__ out) {
  const int tid = threadIdx.x;
  const int wid = tid >> 6, lane = tid & 63;
  const int lo = lane & 15, g = lane >> 4;
  const int bid = blockIdx.x;
  const int xb = ((bid & 7) << 6) | (bid >> 3);   // 512 blocks, bijective
  const int b = xb >> 7;
  const int iw = (xb & 127) * 32;

  __shared__ float OS[3][4096];
  __shared__ float OL[3][512];
  __shared__ float MS[3][32];

  // j-tile range for this wave: 128 tiles over 6 waves -> 22,22,21,21,21,21
  const int ntile = (wid < 2) ? 22 : 21;
  const int tbase = wid * 21 + (wid < 2 ? wid : 2);

  const short* qB = ql + (size_t)b * (SEQ * 32) + (size_t)tbase * 1024;
  const short* vB = vfb + (size_t)b * (SEQ * 128) + (size_t)tbase * 4096;

  bf16x8 kf[2];
#pragma unroll
  for (int c = 0; c < 2; ++c)
    kf[c] = *(const bf16x8*)(kb + (size_t)(b * SEQ + iw + 16 * c + lo) * C4D + g * 8);

  f32x4 o[2][8];
#pragma unroll
  for (int c = 0; c < 2; ++c)
#pragma unroll
    for (int n = 0; n < 8; ++n) o[c][n] = (f32x4){0.f, 0.f, 0.f, 0.f};
  f32x4 olv[2];
  olv[0] = (f32x4){0.f, 0.f, 0.f, 0.f};
  olv[1] = (f32x4){0.f, 0.f, 0.f, 0.f};

  float ma[2];
  const f32x4 zf = {0.f, 0.f, 0.f, 0.f};
  bf16x8 ones;
#pragma unroll
  for (int e = 0; e < 8; ++e) ones[e] = (short)0x3F80;   // bf16 1.0

  bf16x8 pf[2];

  // prologue: Q tile 0
  bf16x8 qf0 = *(const bf16x8*)(qB + lane * 8);
  bf16x8 qf1 = *(const bf16x8*)(qB + 512 + lane * 8);

  // ---- tile 0 (peeled): exact per-row max, then process ----
  {
    bf16x8 va[4];
#pragma unroll
    for (int n = 0; n < 4; ++n)
      va[n] = *(const bf16x8*)(vB + n * 512 + lane * 8);

    f32x4 s0[2], s1[2];
    __builtin_amdgcn_s_setprio(1);
#pragma unroll
    for (int c = 0; c < 2; ++c) {
      s0[c] = mfma16(qf0, kf[c], zf);
      s1[c] = mfma16(qf1, kf[c], zf);
    }
    __builtin_amdgcn_s_setprio(0);

    bf16x8 vb_[4];
#pragma unroll
    for (int n = 0; n < 4; ++n)
      vb_[n] = *(const bf16x8*)(vB + (4 + n) * 512 + lane * 8);

    // Q prefetch for t=1
    qf0 = *(const bf16x8*)(qB + 1024 + lane * 8);
    qf1 = *(const bf16x8*)(qB + 1536 + lane * 8);

#pragma unroll
    for (int c = 0; c < 2; ++c) {
      float tm = fmaxf(fmaxf(fmaxf(s0[c][0], s0[c][1]), fmaxf(s0[c][2], s0[c][3])),
                       fmaxf(fmaxf(s1[c][0], s1[c][1]), fmaxf(s1[c][2], s1[c][3])));
      tm = fmaxf(tm, __shfl_xor(tm, 16, 64));
      tm = fmaxf(tm, __shfl_xor(tm, 32, 64));
      ma[c] = tm;                       // frozen for the whole pass
    }

#pragma unroll
    for (int c = 0; c < 2; ++c) {
      float p[8];
#pragma unroll
      for (int r = 0; r < 4; ++r) {
        p[r]     = fast_exp2(s0[c][r] - ma[c]);
        p[4 + r] = fast_exp2(s1[c][r] - ma[c]);
      }
      union { bf16x8 v8; unsigned u[4]; } pk;
      pk.u[0] = cvt_pk_bf16(p[0], p[1]);
      pk.u[1] = cvt_pk_bf16(p[2], p[3]);
      pk.u[2] = cvt_pk_bf16(p[4], p[5]);
      pk.u[3] = cvt_pk_bf16(p[6], p[7]);
      pf[c] = pk.v8;
    }

    __builtin_amdgcn_s_setprio(1);
#pragma unroll
    for (int n = 0; n < 4; ++n) {
      o[0][n] = mfma16(pf[0], va[n], o[0][n]);
      o[1][n] = mfma16(pf[1], va[n], o[1][n]);
    }
#pragma unroll
    for (int n = 0; n < 4; ++n) {
      o[0][4 + n] = mfma16(pf[0], vb_[n], o[0][4 + n]);
      o[1][4 + n] = mfma16(pf[1], vb_[n], o[1][4 + n]);
    }
    olv[0] = mfma16(pf[0], ones, olv[0]);
    olv[1] = mfma16(pf[1], ones, olv[1]);
    __builtin_amdgcn_s_setprio(0);
  }

  // ---- main loop: branch-free, runtime bound (wave-uniform) ----
  for (int t = 1; t < ntile; ++t) {
    const short* vt = vB + (size_t)t * 4096;
    bf16x8 va[4];
#pragma unroll
    for (int n = 0; n < 4; ++n)
      va[n] = *(const bf16x8*)(vt + n * 512 + lane * 8);

    f32x4 s0[2], s1[2];
    __builtin_amdgcn_s_setprio(1);
#pragma unroll
    for (int c = 0; c < 2; ++c) {
      s0[c] = mfma16(qf0, kf[c], zf);
      s1[c] = mfma16(qf1, kf[c], zf);
    }
    __builtin_amdgcn_s_setprio(0);

    bf16x8 vb_[4];
#pragma unroll
    for (int n = 0; n < 4; ++n)
      vb_[n] = *(const bf16x8*)(vt + (4 + n) * 512 + lane * 8);

    if (t + 1 < ntile) {
      const short* qt = qB + (size_t)(t + 1) * 1024;
      qf0 = *(const bf16x8*)(qt + lane * 8);
      qf1 = *(const bf16x8*)(qt + 512 + lane * 8);
    }

#pragma unroll
    for (int c = 0; c < 2; ++c) {
      float p[8];
#pragma unroll
      for (int r = 0; r < 4; ++r) {
        p[r]     = fast_exp2(s0[c][r] - ma[c]);
        p[4 + r] = fast_exp2(s1[c][r] - ma[c]);
      }
      union { bf16x8 v8; unsigned u[4]; } pk;
      pk.u[0] = cvt_pk_bf16(p[0], p[1]);
      pk.u[1] = cvt_pk_bf16(p[2], p[3]);
      pk.u[2] = cvt_pk_bf16(p[4], p[5]);
      pk.u[3] = cvt_pk_bf16(p[6], p[7]);
      pf[c] = pk.v8;
    }

    __builtin_amdgcn_s_setprio(1);
#pragma unroll
    for (int n = 0; n < 4; ++n) {
      o[0][n] = mfma16(pf[0], va[n], o[0][n]);
      o[1][n] = mfma16(pf[1], va[n], o[1][n]);
    }
#pragma unroll
    for (int n = 0; n < 4; ++n) {
      o[0][4 + n] = mfma16(pf[0], vb_[n], o[0][4 + n]);
      o[1][4 + n] = mfma16(pf[1], vb_[n], o[1][4 + n]);
    }
    olv[0] = mfma16(pf[0], ones, olv[0]);
    olv[1] = mfma16(pf[1], ones, olv[1]);
    __builtin_amdgcn_s_setprio(0);
  }

  auto write_slot = [&](int s) {
#pragma unroll
    for (int c = 0; c < 2; ++c)
#pragma unroll
      for (int n = 0; n < 8; ++n)
        *(f32x4*)&OS[s][(c * 8 + n) * 256 + lane * 4] = o[c][n];
#pragma unroll
    for (int c = 0; c < 2; ++c)
      *(f32x4*)&OL[s][c * 256 + lane * 4] = olv[c];
    if (lane < 16) {
#pragma unroll
      for (int c = 0; c < 2; ++c) MS[s][c * 16 + lo] = ma[c];
    }
  };
  auto merge_slot = [&](int s) {
#pragma unroll
    for (int c = 0; c < 2; ++c) {
      float ms = MS[s][c * 16 + lo];
      float M = fmaxf(ma[c], ms);
      float eo = fast_exp2(ma[c] - M), es = fast_exp2(ms - M);
      ma[c] = M;
      float eor[4], esr[4];
#pragma unroll
      for (int r = 0; r < 4; ++r) {
        eor[r] = __shfl(eo, 4 * g + r, 64);
        esr[r] = __shfl(es, 4 * g + r, 64);
      }
#pragma unroll
      for (int n = 0; n < 8; ++n) {
        f32x4 v = *(f32x4*)&OS[s][(c * 8 + n) * 256 + lane * 4];
#pragma unroll
        for (int r = 0; r < 4; ++r)
          o[c][n][r] = eor[r] * o[c][n][r] + esr[r] * v[r];
      }
      f32x4 vl = *(f32x4*)&OL[s][c * 256 + lane * 4];
#pragma unroll
      for (int r = 0; r < 4; ++r)
        olv[c][r] = eor[r] * olv[c][r] + esr[r] * vl[r];
    }
  };

  // 6-wave merge: (w0<-w1), (w2<-w3), (w4<-w5); then w0 <- w2, w4.
  if (wid == 1) write_slot(0);
  if (wid == 3) write_slot(1);
  if (wid == 5) write_slot(2);
  __syncthreads();
  if (wid == 0) merge_slot(0);
  if (wid == 2) merge_slot(1);
  if (wid == 4) merge_slot(2);
  __syncthreads();
  if (wid == 2) write_slot(0);
  if (wid == 4) write_slot(1);
  __syncthreads();
  if (wid == 0) {
    merge_slot(0);
    merge_slot(1);
    float* outp = out + (size_t)(b * SEQ + iw) * OUTC;
#pragma unroll
    for (int c = 0; c < 2; ++c) {
      float lir[4];
#pragma unroll
      for (int r = 0; r < 4; ++r) lir[r] = 1.f / olv[c][r];
#pragma unroll
      for (int n = 0; n < 8; ++n) {
        float bu = bias[n * 16 + lo];
#pragma unroll
        for (int r = 0; r < 4; ++r)
          outp[(size_t)(c * 16 + 4 * g + r) * OUTC + n * 16 + lo] =
              o[c][n][r] * lir[r] + bu;
      }
    }
  }
}

// ---------------------------------------------------------------------------
extern "C" void kernel_launch(void* const* d_in, const int* in_sizes, int n_in,
                              void* d_out, int out_size, void* d_ws, size_t ws_size,
                              hipStream_t stream) {
  (void)in_sizes; (void)n_in; (void)out_size; (void)ws_size;
  const float* x      = (const float*)d_in[0];
  const float* weight = (const float*)d_in[1];
  const float* bias   = (const float*)d_in[2];
  const float* wq     = (const float*)d_in[3];
  const float* bq     = (const float*)d_in[4];
  const float* wk     = (const float*)d_in[5];
  const float* bk     = (const float*)d_in[6];
  const float* wv     = (const float*)d_in[7];
  const float* bv     = (const float*)d_in[8];
  float* out = (float*)d_out;

  char* ws = (char*)d_ws;
  short* kbuf = (short*)(ws);                                   // 1 MiB [p][32]
  short* vfb  = (short*)(ws + ((size_t)1 << 20));               // 4 MiB VF tiles
  short* qlb  = (short*)(ws + ((size_t)5 << 20));               // 1 MiB QL tiles
  // wqb|wkb|wfT form one contiguous 48KB "wall" used by k_proj
  short* wqb  = (short*)(ws + ((size_t)6 << 20));               // 8 KiB
  short* wkb  = (short*)(ws + ((size_t)6 << 20) + 8192);        // 8 KiB
  short* wfT  = (short*)(ws + ((size_t)6 << 20) + 16384);       // 32 KiB
  float* bfu  = (float*)(ws + ((size_t)6 << 20) + 49152);       // 512 B

  hipLaunchKernelGGL(k_fuse, dim3(OUTC), dim3(CIN), 0, stream,
                     wq, wk, wv, weight, bv, wqb, wkb, wfT, bfu);
  hipLaunchKernelGGL(k_proj, dim3(NB * SEQ / 64), dim3(256), 0, stream,
                     x, bq, bk, wqb /* = wall */, bfu, qlb, kbuf, vfb);
  hipLaunchKernelGGL(k_attn, dim3(NB * SEQ / 32), dim3(384), 0, stream,
                     qlb, kbuf, vfb, bias, out);
}

// Round 18
// 50.659 us; speedup vs baseline: 1.0364x; 1.0364x over previous
//
#include <hip/hip_runtime.h>

#define NB   4
#define SEQ  4096
#define CIN  128
#define C4D  32
#define OUTC 128
#define LOG2E 1.44269504f

typedef __attribute__((ext_vector_type(8))) short bf16x8;
typedef __attribute__((ext_vector_type(4))) float f32x4;

__device__ __forceinline__ short f2bf(float f) {
  union { float f; unsigned u; } v; v.f = f;
  unsigned r = v.u + 0x7FFFu + ((v.u >> 16) & 1u);
  return (short)(r >> 16);
}

__device__ __forceinline__ unsigned cvt_pk_bf16(float lo, float hi) {
  unsigned r;
  asm("v_cvt_pk_bf16_f32 %0, %1, %2" : "=v"(r) : "v"(lo), "v"(hi));
  return r;
}

// native 2^x (v_exp_f32) — exp2f() without fast-math lowers to slow OCML.
__device__ __forceinline__ float fast_exp2(float x) {
  float r;
  asm("v_exp_f32 %0, %1" : "=v"(r) : "v"(x));
  return r;
}

__device__ __forceinline__ f32x4 mfma16(bf16x8 a, bf16x8 b, f32x4 c) {
  return __builtin_amdgcn_mfma_f32_16x16x32_bf16(a, b, c, 0, 0, 0);
}

// ---------------------------------------------------------------------------
// Kernel 1: fold value-path weights (unchanged).
// ---------------------------------------------------------------------------
__global__ void k_fuse(const float* __restrict__ wq, const float* __restrict__ wk,
                       const float* __restrict__ wv, const float* __restrict__ weight,
                       const float* __restrict__ bv,
                       short* __restrict__ wqb, short* __restrict__ wkb,
                       short* __restrict__ wfT, float* __restrict__ bfu) {
  int u = blockIdx.x, c = threadIdx.x;
  float a0 = 0.f, a1 = 0.f, a2 = 0.f, a3 = 0.f;
  for (int o = 0; o < OUTC; o += 4) {
    a0 += wv[(o + 0) * CIN + c] * weight[(o + 0) * OUTC + u];
    a1 += wv[(o + 1) * CIN + c] * weight[(o + 1) * OUTC + u];
    a2 += wv[(o + 2) * CIN + c] * weight[(o + 2) * OUTC + u];
    a3 += wv[(o + 3) * CIN + c] * weight[(o + 3) * OUTC + u];
  }
  wfT[u * CIN + c] = f2bf((a0 + a1) + (a2 + a3));
  if (u < C4D) {
    wqb[u * CIN + c] = f2bf(wq[u * CIN + c]);
    wkb[u * CIN + c] = f2bf(wk[u * CIN + c]);
  }
  if (c == 0) {
    float b0 = 0.f, b1 = 0.f;
    for (int o = 0; o < OUTC; o += 2) {
      b0 += bv[o] * weight[o * OUTC + u];
      b1 += bv[o + 1] * weight[(o + 1) * OUTC + u];
    }
    bfu[u] = b0 + b1;
  }
}

// ---------------------------------------------------------------------------
// Kernel 2: projections, K-SPLIT for occupancy. Block = 4 waves / 32
// positions: waves {0,1} handle kk in {0,1} for position-halves {0,1};
// waves {2,3} handle kk in {2,3}. Waves 2-3 write their 12 partial f32x4
// accumulators to LDS (fragment-major, conflict-free); waves 0-1 add and
// run the epilogue. Grid 512 blocks -> 2 waves/SIMD (was 1). Weights
// LDS-staged with XOR swizzle as before. K pre-scaled by log2(e).
// ---------------------------------------------------------------------------
__device__ __forceinline__ int wswz(int byte) {
  return byte ^ (((byte >> 8) & 7) << 4);
}

__global__ __launch_bounds__(256) void k_proj(
    const float* __restrict__ x, const float* __restrict__ bq, const float* __restrict__ bk,
    const short* __restrict__ wall, const float* __restrict__ bfu,
    short* __restrict__ ql, short* __restrict__ kb, short* __restrict__ vfb) {
  const int tid = threadIdx.x;
  const int wid = tid >> 6, lane = tid & 63;
  const int lo = lane & 15, g = lane >> 4;
  const int wp = wid & 1;            // position half (0/1)
  const int wkh = wid >> 1;          // k half: 0 -> kk 0..1, 1 -> kk 2..3
  const int p0 = blockIdx.x * 32 + wp * 16;

  __shared__ __align__(16) short WL[24576];      // 48KB swizzled weights
  __shared__ __align__(16) float PS[12][128][4]; // 24KB k-half partials

  // stage weights (all 256 threads, 12 x 16B each)
#pragma unroll
  for (int i = 0; i < 12; ++i) {
    bf16x8 v = *(const bf16x8*)(wall + i * 2048 + tid * 8);
    *(bf16x8*)((char*)WL + wswz((i * 2048 + tid * 8) * 2)) = v;
  }
  __syncthreads();

  auto wfrag = [&](int idx) -> bf16x8 {
    return *(const bf16x8*)((char*)WL + wswz(idx * 2));
  };

  f32x4 aq[2] = {}, ak[2] = {}, as_[8] = {};

#pragma unroll
  for (int kx = 0; kx < 2; ++kx) {
    const int kk = wkh * 2 + kx;
    const float* xp = x + (size_t)(p0 + lo) * CIN + kk * 32 + g * 8;
    float4 xa = *(const float4*)xp;
    float4 xb = *(const float4*)(xp + 4);
    bf16x8 af;
    af[0] = f2bf(xa.x); af[1] = f2bf(xa.y); af[2] = f2bf(xa.z); af[3] = f2bf(xa.w);
    af[4] = f2bf(xb.x); af[5] = f2bf(xb.y); af[6] = f2bf(xb.z); af[7] = f2bf(xb.w);
#pragma unroll
    for (int n = 0; n < 2; ++n) {
      bf16x8 bq_ = wfrag((n * 16 + lo) * CIN + kk * 32 + g * 8);
      aq[n] = mfma16(af, bq_, aq[n]);
      bf16x8 bk_ = wfrag(4096 + (n * 16 + lo) * CIN + kk * 32 + g * 8);
      ak[n] = mfma16(af, bk_, ak[n]);
    }
#pragma unroll
    for (int n = 0; n < 8; ++n) {
      bf16x8 bs = wfrag(8192 + (n * 16 + lo) * CIN + kk * 32 + g * 8);
      as_[n] = mfma16(af, bs, as_[n]);
    }
  }

  const int idx = wp * 64 + lane;
  if (wkh == 1) {
    *(f32x4*)&PS[0][idx][0] = aq[0];
    *(f32x4*)&PS[1][idx][0] = aq[1];
    *(f32x4*)&PS[2][idx][0] = ak[0];
    *(f32x4*)&PS[3][idx][0] = ak[1];
#pragma unroll
    for (int n = 0; n < 8; ++n) *(f32x4*)&PS[4 + n][idx][0] = as_[n];
  }
  __syncthreads();
  if (wkh == 1) return;

  aq[0] += *(f32x4*)&PS[0][idx][0];
  aq[1] += *(f32x4*)&PS[1][idx][0];
  ak[0] += *(f32x4*)&PS[2][idx][0];
  ak[1] += *(f32x4*)&PS[3][idx][0];
#pragma unroll
  for (int n = 0; n < 8; ++n) as_[n] += *(f32x4*)&PS[4 + n][idx][0];

#pragma unroll
  for (int n = 0; n < 2; ++n) {
    float bqv = bq[n * 16 + lo], bkv = bk[n * 16 + lo];
    int u = n * 16 + lo;
#pragma unroll
    for (int r = 0; r < 4; ++r) {
      int p = p0 + 4 * g + r;
      int bb = p >> 12, s = p & (SEQ - 1);
      ql[(size_t)bb * (SEQ * 32) + (size_t)(s >> 5) * 1024 + ((s >> 4) & 1) * 512 +
         (u >> 3) * 128 + (s & 15) * 8 + (u & 7)] = f2bf(aq[n][r] + bqv);
      kb[(size_t)p * C4D + u] = f2bf((ak[n][r] + bkv) * LOG2E);
    }
  }
  {
    const int p = p0 + 4 * g;          // r = 0; r=0..3 contiguous in VF
    const int bb = p >> 12, s = p & (SEQ - 1);
#pragma unroll
    for (int n = 0; n < 8; ++n) {
      int u = n * 16 + lo;
      float bvv = bfu[u];
      uint2 w;
      w.x = cvt_pk_bf16(as_[n][0] + bvv, as_[n][1] + bvv);
      w.y = cvt_pk_bf16(as_[n][2] + bvv, as_[n][3] + bvv);
      *(uint2*)&vfb[(size_t)bb * (SEQ * 128) + (size_t)(s >> 5) * 4096 + (u >> 4) * 512 +
                    ((s >> 2) & 3) * 128 + (u & 15) * 8 + ((s >> 4) & 1) * 4] = w;
    }
  }
}

// ---------------------------------------------------------------------------
// Kernel 3 (Design III, R16 version — reverted from R17's 6-wave regression):
// wave = 32 i-rows, 4 waves/block, j-split 4, 32 iters. Frozen-max (tile-0
// peeled), branch-free main loop, l via ones-MFMA, direct-global V.
// ---------------------------------------------------------------------------
__global__ __launch_bounds__(256, 3) void k_attn(
    const short* __restrict__ ql, const short* __restrict__ kb,
    const short* __restrict__ vfb, const float* __restrict__ bias,
    float* __restrict__ out) {
  const int tid = threadIdx.x;
  const int wid = tid >> 6, lane = tid & 63;
  const int lo = lane & 15, g = lane >> 4;
  const int bid = blockIdx.x;
  const int xb = ((bid & 7) << 6) | (bid >> 3);   // 512 blocks, bijective
  const int b = xb >> 7;
  const int iw = (xb & 127) * 32;

  __shared__ float OS[2][4096];
  __shared__ float OL[2][512];
  __shared__ float MS[2][32];

  const short* qB = ql + (size_t)b * (SEQ * 32) + (size_t)wid * 32768;
  const short* vB = vfb + (size_t)b * (SEQ * 128) + (size_t)wid * 131072;

  bf16x8 kf[2];
#pragma unroll
  for (int c = 0; c < 2; ++c)
    kf[c] = *(const bf16x8*)(kb + (size_t)(b * SEQ + iw + 16 * c + lo) * C4D + g * 8);

  f32x4 o[2][8];
#pragma unroll
  for (int c = 0; c < 2; ++c)
#pragma unroll
    for (int n = 0; n < 8; ++n) o[c][n] = (f32x4){0.f, 0.f, 0.f, 0.f};
  f32x4 olv[2];
  olv[0] = (f32x4){0.f, 0.f, 0.f, 0.f};
  olv[1] = (f32x4){0.f, 0.f, 0.f, 0.f};

  float ma[2];
  const f32x4 zf = {0.f, 0.f, 0.f, 0.f};
  bf16x8 ones;
#pragma unroll
  for (int e = 0; e < 8; ++e) ones[e] = (short)0x3F80;   // bf16 1.0

  bf16x8 pf[2];

  // prologue: Q tile 0
  bf16x8 qf0 = *(const bf16x8*)(qB + lane * 8);
  bf16x8 qf1 = *(const bf16x8*)(qB + 512 + lane * 8);

  // ---- tile 0 (peeled): exact per-row max, then process ----
  {
    bf16x8 vfr[8];
#pragma unroll
    for (int n = 0; n < 8; ++n)
      vfr[n] = *(const bf16x8*)(vB + n * 512 + lane * 8);

    f32x4 s0[2], s1[2];
    __builtin_amdgcn_s_setprio(1);
#pragma unroll
    for (int c = 0; c < 2; ++c) {
      s0[c] = mfma16(qf0, kf[c], zf);
      s1[c] = mfma16(qf1, kf[c], zf);
    }
    __builtin_amdgcn_s_setprio(0);

    // Q prefetch for t=1
    qf0 = *(const bf16x8*)(qB + 1024 + lane * 8);
    qf1 = *(const bf16x8*)(qB + 1536 + lane * 8);

#pragma unroll
    for (int c = 0; c < 2; ++c) {
      float tm = fmaxf(fmaxf(fmaxf(s0[c][0], s0[c][1]), fmaxf(s0[c][2], s0[c][3])),
                       fmaxf(fmaxf(s1[c][0], s1[c][1]), fmaxf(s1[c][2], s1[c][3])));
      tm = fmaxf(tm, __shfl_xor(tm, 16, 64));
      tm = fmaxf(tm, __shfl_xor(tm, 32, 64));
      ma[c] = tm;                       // frozen for the whole pass
    }

#pragma unroll
    for (int c = 0; c < 2; ++c) {
      float p[8];
#pragma unroll
      for (int r = 0; r < 4; ++r) {
        p[r]     = fast_exp2(s0[c][r] - ma[c]);
        p[4 + r] = fast_exp2(s1[c][r] - ma[c]);
      }
      union { bf16x8 v8; unsigned u[4]; } pk;
      pk.u[0] = cvt_pk_bf16(p[0], p[1]);
      pk.u[1] = cvt_pk_bf16(p[2], p[3]);
      pk.u[2] = cvt_pk_bf16(p[4], p[5]);
      pk.u[3] = cvt_pk_bf16(p[6], p[7]);
      pf[c] = pk.v8;
    }

    __builtin_amdgcn_s_setprio(1);
#pragma unroll
    for (int n = 0; n < 8; ++n) {
      o[0][n] = mfma16(pf[0], vfr[n], o[0][n]);
      o[1][n] = mfma16(pf[1], vfr[n], o[1][n]);
    }
    olv[0] = mfma16(pf[0], ones, olv[0]);
    olv[1] = mfma16(pf[1], ones, olv[1]);
    __builtin_amdgcn_s_setprio(0);
  }

  // ---- main loop: branch-free ----
  for (int t = 1; t < 32; ++t) {
    bf16x8 vfr[8];
    const short* vt = vB + (size_t)t * 4096;
#pragma unroll
    for (int n = 0; n < 8; ++n)
      vfr[n] = *(const bf16x8*)(vt + n * 512 + lane * 8);

    f32x4 s0[2], s1[2];
    __builtin_amdgcn_s_setprio(1);
#pragma unroll
    for (int c = 0; c < 2; ++c) {
      s0[c] = mfma16(qf0, kf[c], zf);
      s1[c] = mfma16(qf1, kf[c], zf);
    }
    __builtin_amdgcn_s_setprio(0);

    if (t + 1 < 32) {
      const short* qt = qB + (size_t)(t + 1) * 1024;
      qf0 = *(const bf16x8*)(qt + lane * 8);
      qf1 = *(const bf16x8*)(qt + 512 + lane * 8);
    }

#pragma unroll
    for (int c = 0; c < 2; ++c) {
      float p[8];
#pragma unroll
      for (int r = 0; r < 4; ++r) {
        p[r]     = fast_exp2(s0[c][r] - ma[c]);
        p[4 + r] = fast_exp2(s1[c][r] - ma[c]);
      }
      union { bf16x8 v8; unsigned u[4]; } pk;
      pk.u[0] = cvt_pk_bf16(p[0], p[1]);
      pk.u[1] = cvt_pk_bf16(p[2], p[3]);
      pk.u[2] = cvt_pk_bf16(p[4], p[5]);
      pk.u[3] = cvt_pk_bf16(p[6], p[7]);
      pf[c] = pk.v8;
    }

    __builtin_amdgcn_s_setprio(1);
#pragma unroll
    for (int n = 0; n < 8; ++n) {
      o[0][n] = mfma16(pf[0], vfr[n], o[0][n]);
      o[1][n] = mfma16(pf[1], vfr[n], o[1][n]);
    }
    olv[0] = mfma16(pf[0], ones, olv[0]);
    olv[1] = mfma16(pf[1], ones, olv[1]);
    __builtin_amdgcn_s_setprio(0);
  }

  auto write_slot = [&](int s) {
#pragma unroll
    for (int c = 0; c < 2; ++c)
#pragma unroll
      for (int n = 0; n < 8; ++n)
        *(f32x4*)&OS[s][(c * 8 + n) * 256 + lane * 4] = o[c][n];
#pragma unroll
    for (int c = 0; c < 2; ++c)
      *(f32x4*)&OL[s][c * 256 + lane * 4] = olv[c];
    if (lane < 16) {
#pragma unroll
      for (int c = 0; c < 2; ++c) MS[s][c * 16 + lo] = ma[c];
    }
  };
  auto merge_slot = [&](int s) {
#pragma unroll
    for (int c = 0; c < 2; ++c) {
      float ms = MS[s][c * 16 + lo];
      float M = fmaxf(ma[c], ms);
      float eo = fast_exp2(ma[c] - M), es = fast_exp2(ms - M);
      ma[c] = M;
      float eor[4], esr[4];
#pragma unroll
      for (int r = 0; r < 4; ++r) {
        eor[r] = __shfl(eo, 4 * g + r, 64);
        esr[r] = __shfl(es, 4 * g + r, 64);
      }
#pragma unroll
      for (int n = 0; n < 8; ++n) {
        f32x4 v = *(f32x4*)&OS[s][(c * 8 + n) * 256 + lane * 4];
#pragma unroll
        for (int r = 0; r < 4; ++r)
          o[c][n][r] = eor[r] * o[c][n][r] + esr[r] * v[r];
      }
      f32x4 vl = *(f32x4*)&OL[s][c * 256 + lane * 4];
#pragma unroll
      for (int r = 0; r < 4; ++r)
        olv[c][r] = eor[r] * olv[c][r] + esr[r] * vl[r];
    }
  };

  if (wid == 1) write_slot(0);
  if (wid == 3) write_slot(1);
  __syncthreads();
  if (wid == 0) merge_slot(0);
  if (wid == 2) merge_slot(1);
  __syncthreads();
  if (wid == 2) write_slot(0);
  __syncthreads();
  if (wid == 0) {
    merge_slot(0);
    float* outp = out + (size_t)(b * SEQ + iw) * OUTC;
#pragma unroll
    for (int c = 0; c < 2; ++c) {
      float lir[4];
#pragma unroll
      for (int r = 0; r < 4; ++r) lir[r] = 1.f / olv[c][r];
#pragma unroll
      for (int n = 0; n < 8; ++n) {
        float bu = bias[n * 16 + lo];
#pragma unroll
        for (int r = 0; r < 4; ++r)
          outp[(size_t)(c * 16 + 4 * g + r) * OUTC + n * 16 + lo] =
              o[c][n][r] * lir[r] + bu;
      }
    }
  }
}

// ---------------------------------------------------------------------------
extern "C" void kernel_launch(void* const* d_in, const int* in_sizes, int n_in,
                              void* d_out, int out_size, void* d_ws, size_t ws_size,
                              hipStream_t stream) {
  (void)in_sizes; (void)n_in; (void)out_size; (void)ws_size;
  const float* x      = (const float*)d_in[0];
  const float* weight = (const float*)d_in[1];
  const float* bias   = (const float*)d_in[2];
  const float* wq     = (const float*)d_in[3];
  const float* bq     = (const float*)d_in[4];
  const float* wk     = (const float*)d_in[5];
  const float* bk     = (const float*)d_in[6];
  const float* wv     = (const float*)d_in[7];
  const float* bv     = (const float*)d_in[8];
  float* out = (float*)d_out;

  char* ws = (char*)d_ws;
  short* kbuf = (short*)(ws);                                   // 1 MiB [p][32]
  short* vfb  = (short*)(ws + ((size_t)1 << 20));               // 4 MiB VF tiles
  short* qlb  = (short*)(ws + ((size_t)5 << 20));               // 1 MiB QL tiles
  // wqb|wkb|wfT form one contiguous 48KB "wall" used by k_proj
  short* wqb  = (short*)(ws + ((size_t)6 << 20));               // 8 KiB
  short* wkb  = (short*)(ws + ((size_t)6 << 20) + 8192);        // 8 KiB
  short* wfT  = (short*)(ws + ((size_t)6 << 20) + 16384);       // 32 KiB
  float* bfu  = (float*)(ws + ((size_t)6 << 20) + 49152);       // 512 B

  hipLaunchKernelGGL(k_fuse, dim3(OUTC), dim3(CIN), 0, stream,
                     wq, wk, wv, weight, bv, wqb, wkb, wfT, bfu);
  hipLaunchKernelGGL(k_proj, dim3(NB * SEQ / 32), dim3(256), 0, stream,
                     x, bq, bk, wqb /* = wall */, bfu, qlb, kbuf, vfb);
  hipLaunchKernelGGL(k_attn, dim3(NB * SEQ / 32), dim3(256), 0, stream,
                     qlb, kbuf, vfb, bias, out);
}

// Round 19
// 49.400 us; speedup vs baseline: 1.0628x; 1.0255x over previous
//
#include <hip/hip_runtime.h>

#define NB   4
#define SEQ  4096
#define CIN  128
#define C4D  32
#define OUTC 128
#define LOG2E 1.44269504f

typedef __attribute__((ext_vector_type(8))) short bf16x8;
typedef __attribute__((ext_vector_type(4))) float f32x4;

__device__ __forceinline__ short f2bf(float f) {
  union { float f; unsigned u; } v; v.f = f;
  unsigned r = v.u + 0x7FFFu + ((v.u >> 16) & 1u);
  return (short)(r >> 16);
}

__device__ __forceinline__ unsigned cvt_pk_bf16(float lo, float hi) {
  unsigned r;
  asm("v_cvt_pk_bf16_f32 %0, %1, %2" : "=v"(r) : "v"(lo), "v"(hi));
  return r;
}

// native 2^x (v_exp_f32) — exp2f() without fast-math lowers to slow OCML.
__device__ __forceinline__ float fast_exp2(float x) {
  float r;
  asm("v_exp_f32 %0, %1" : "=v"(r) : "v"(x));
  return r;
}

__device__ __forceinline__ f32x4 mfma16(bf16x8 a, bf16x8 b, f32x4 c) {
  return __builtin_amdgcn_mfma_f32_16x16x32_bf16(a, b, c, 0, 0, 0);
}

// ---------------------------------------------------------------------------
// Kernel 1: fold value-path weights (unchanged).
// ---------------------------------------------------------------------------
__global__ void k_fuse(const float* __restrict__ wq, const float* __restrict__ wk,
                       const float* __restrict__ wv, const float* __restrict__ weight,
                       const float* __restrict__ bv,
                       short* __restrict__ wqb, short* __restrict__ wkb,
                       short* __restrict__ wfT, float* __restrict__ bfu) {
  int u = blockIdx.x, c = threadIdx.x;
  float a0 = 0.f, a1 = 0.f, a2 = 0.f, a3 = 0.f;
  for (int o = 0; o < OUTC; o += 4) {
    a0 += wv[(o + 0) * CIN + c] * weight[(o + 0) * OUTC + u];
    a1 += wv[(o + 1) * CIN + c] * weight[(o + 1) * OUTC + u];
    a2 += wv[(o + 2) * CIN + c] * weight[(o + 2) * OUTC + u];
    a3 += wv[(o + 3) * CIN + c] * weight[(o + 3) * OUTC + u];
  }
  wfT[u * CIN + c] = f2bf((a0 + a1) + (a2 + a3));
  if (u < C4D) {
    wqb[u * CIN + c] = f2bf(wq[u * CIN + c]);
    wkb[u * CIN + c] = f2bf(wk[u * CIN + c]);
  }
  if (c == 0) {
    float b0 = 0.f, b1 = 0.f;
    for (int o = 0; o < OUTC; o += 2) {
      b0 += bv[o] * weight[o * OUTC + u];
      b1 += bv[o + 1] * weight[(o + 1) * OUTC + u];
    }
    bfu[u] = b0 + b1;
  }
}

// ---------------------------------------------------------------------------
// Kernel 2: projections (R16 structure, 256 blocks / 64 pos). NEW: all 8 x
// loads hoisted to kernel top (issued before the weight-staging barrier ->
// one HBM round-trip instead of 4 serialized ones) and af conversion via
// cvt_pk (4 instrs/fragment). LDS-swizzled weights; K pre-scaled by log2e.
// ---------------------------------------------------------------------------
__device__ __forceinline__ int wswz(int byte) {
  return byte ^ (((byte >> 8) & 7) << 4);
}

__global__ __launch_bounds__(256) void k_proj(
    const float* __restrict__ x, const float* __restrict__ bq, const float* __restrict__ bk,
    const short* __restrict__ wall, const float* __restrict__ bfu,
    short* __restrict__ ql, short* __restrict__ kb, short* __restrict__ vfb) {
  const int tid = threadIdx.x;
  const int wid = tid >> 6, lane = tid & 63;
  const int lo = lane & 15, g = lane >> 4;
  const int p0 = blockIdx.x * 64 + wid * 16;

  __shared__ __align__(16) short WL[24576];   // 48KB swizzled weights

  // hoisted x loads: 8 independent float4 loads, all in flight at once
  float4 xa[4], xb[4];
#pragma unroll
  for (int kk = 0; kk < 4; ++kk) {
    const float* xp = x + (size_t)(p0 + lo) * CIN + kk * 32 + g * 8;
    xa[kk] = *(const float4*)xp;
    xb[kk] = *(const float4*)(xp + 4);
  }

#pragma unroll
  for (int i = 0; i < 12; ++i) {
    bf16x8 v = *(const bf16x8*)(wall + i * 2048 + tid * 8);
    *(bf16x8*)((char*)WL + wswz((i * 2048 + tid * 8) * 2)) = v;
  }
  __syncthreads();

  auto wfrag = [&](int idx) -> bf16x8 {
    return *(const bf16x8*)((char*)WL + wswz(idx * 2));
  };

  // convert x to bf16 fragments (cvt_pk: RNE, 4 instrs per fragment)
  bf16x8 af[4];
#pragma unroll
  for (int kk = 0; kk < 4; ++kk) {
    union { bf16x8 v8; unsigned u[4]; } pk;
    pk.u[0] = cvt_pk_bf16(xa[kk].x, xa[kk].y);
    pk.u[1] = cvt_pk_bf16(xa[kk].z, xa[kk].w);
    pk.u[2] = cvt_pk_bf16(xb[kk].x, xb[kk].y);
    pk.u[3] = cvt_pk_bf16(xb[kk].z, xb[kk].w);
    af[kk] = pk.v8;
  }

  f32x4 aq[2] = {}, ak[2] = {}, as_[8] = {};

#pragma unroll
  for (int kk = 0; kk < 4; ++kk) {
#pragma unroll
    for (int n = 0; n < 2; ++n) {
      bf16x8 bq_ = wfrag((n * 16 + lo) * CIN + kk * 32 + g * 8);
      aq[n] = mfma16(af[kk], bq_, aq[n]);
      bf16x8 bk_ = wfrag(4096 + (n * 16 + lo) * CIN + kk * 32 + g * 8);
      ak[n] = mfma16(af[kk], bk_, ak[n]);
    }
#pragma unroll
    for (int n = 0; n < 8; ++n) {
      bf16x8 bs = wfrag(8192 + (n * 16 + lo) * CIN + kk * 32 + g * 8);
      as_[n] = mfma16(af[kk], bs, as_[n]);
    }
  }

#pragma unroll
  for (int n = 0; n < 2; ++n) {
    float bqv = bq[n * 16 + lo], bkv = bk[n * 16 + lo];
    int u = n * 16 + lo;
#pragma unroll
    for (int r = 0; r < 4; ++r) {
      int p = p0 + 4 * g + r;
      int bb = p >> 12, s = p & (SEQ - 1);
      ql[(size_t)bb * (SEQ * 32) + (size_t)(s >> 5) * 1024 + ((s >> 4) & 1) * 512 +
         (u >> 3) * 128 + (s & 15) * 8 + (u & 7)] = f2bf(aq[n][r] + bqv);
      kb[(size_t)p * C4D + u] = f2bf((ak[n][r] + bkv) * LOG2E);
    }
  }
  {
    const int p = p0 + 4 * g;          // r = 0; r=0..3 contiguous in VF
    const int bb = p >> 12, s = p & (SEQ - 1);
#pragma unroll
    for (int n = 0; n < 8; ++n) {
      int u = n * 16 + lo;
      float bvv = bfu[u];
      uint2 w;
      w.x = cvt_pk_bf16(as_[n][0] + bvv, as_[n][1] + bvv);
      w.y = cvt_pk_bf16(as_[n][2] + bvv, as_[n][3] + bvv);
      *(uint2*)&vfb[(size_t)bb * (SEQ * 128) + (size_t)(s >> 5) * 4096 + (u >> 4) * 512 +
                    ((s >> 2) & 3) * 128 + (u & 15) * 8 + ((s >> 4) & 1) * 4] = w;
    }
  }
}

// ---------------------------------------------------------------------------
// Kernel 3 (Design III, R16 version — best so far): wave = 32 i-rows,
// 4 waves/block, j-split 4, 32 iters. Frozen-max (tile-0 peeled),
// branch-free main loop, l via ones-MFMA, direct-global V.
// ---------------------------------------------------------------------------
__global__ __launch_bounds__(256, 3) void k_attn(
    const short* __restrict__ ql, const short* __restrict__ kb,
    const short* __restrict__ vfb, const float* __restrict__ bias,
    float* __restrict__ out) {
  const int tid = threadIdx.x;
  const int wid = tid >> 6, lane = tid & 63;
  const int lo = lane & 15, g = lane >> 4;
  const int bid = blockIdx.x;
  const int xb = ((bid & 7) << 6) | (bid >> 3);   // 512 blocks, bijective
  const int b = xb >> 7;
  const int iw = (xb & 127) * 32;

  __shared__ float OS[2][4096];
  __shared__ float OL[2][512];
  __shared__ float MS[2][32];

  const short* qB = ql + (size_t)b * (SEQ * 32) + (size_t)wid * 32768;
  const short* vB = vfb + (size_t)b * (SEQ * 128) + (size_t)wid * 131072;

  bf16x8 kf[2];
#pragma unroll
  for (int c = 0; c < 2; ++c)
    kf[c] = *(const bf16x8*)(kb + (size_t)(b * SEQ + iw + 16 * c + lo) * C4D + g * 8);

  f32x4 o[2][8];
#pragma unroll
  for (int c = 0; c < 2; ++c)
#pragma unroll
    for (int n = 0; n < 8; ++n) o[c][n] = (f32x4){0.f, 0.f, 0.f, 0.f};
  f32x4 olv[2];
  olv[0] = (f32x4){0.f, 0.f, 0.f, 0.f};
  olv[1] = (f32x4){0.f, 0.f, 0.f, 0.f};

  float ma[2];
  const f32x4 zf = {0.f, 0.f, 0.f, 0.f};
  bf16x8 ones;
#pragma unroll
  for (int e = 0; e < 8; ++e) ones[e] = (short)0x3F80;   // bf16 1.0

  bf16x8 pf[2];

  // prologue: Q tile 0
  bf16x8 qf0 = *(const bf16x8*)(qB + lane * 8);
  bf16x8 qf1 = *(const bf16x8*)(qB + 512 + lane * 8);

  // ---- tile 0 (peeled): exact per-row max, then process ----
  {
    bf16x8 vfr[8];
#pragma unroll
    for (int n = 0; n < 8; ++n)
      vfr[n] = *(const bf16x8*)(vB + n * 512 + lane * 8);

    f32x4 s0[2], s1[2];
    __builtin_amdgcn_s_setprio(1);
#pragma unroll
    for (int c = 0; c < 2; ++c) {
      s0[c] = mfma16(qf0, kf[c], zf);
      s1[c] = mfma16(qf1, kf[c], zf);
    }
    __builtin_amdgcn_s_setprio(0);

    // Q prefetch for t=1
    qf0 = *(const bf16x8*)(qB + 1024 + lane * 8);
    qf1 = *(const bf16x8*)(qB + 1536 + lane * 8);

#pragma unroll
    for (int c = 0; c < 2; ++c) {
      float tm = fmaxf(fmaxf(fmaxf(s0[c][0], s0[c][1]), fmaxf(s0[c][2], s0[c][3])),
                       fmaxf(fmaxf(s1[c][0], s1[c][1]), fmaxf(s1[c][2], s1[c][3])));
      tm = fmaxf(tm, __shfl_xor(tm, 16, 64));
      tm = fmaxf(tm, __shfl_xor(tm, 32, 64));
      ma[c] = tm;                       // frozen for the whole pass
    }

#pragma unroll
    for (int c = 0; c < 2; ++c) {
      float p[8];
#pragma unroll
      for (int r = 0; r < 4; ++r) {
        p[r]     = fast_exp2(s0[c][r] - ma[c]);
        p[4 + r] = fast_exp2(s1[c][r] - ma[c]);
      }
      union { bf16x8 v8; unsigned u[4]; } pk;
      pk.u[0] = cvt_pk_bf16(p[0], p[1]);
      pk.u[1] = cvt_pk_bf16(p[2], p[3]);
      pk.u[2] = cvt_pk_bf16(p[4], p[5]);
      pk.u[3] = cvt_pk_bf16(p[6], p[7]);
      pf[c] = pk.v8;
    }

    __builtin_amdgcn_s_setprio(1);
#pragma unroll
    for (int n = 0; n < 8; ++n) {
      o[0][n] = mfma16(pf[0], vfr[n], o[0][n]);
      o[1][n] = mfma16(pf[1], vfr[n], o[1][n]);
    }
    olv[0] = mfma16(pf[0], ones, olv[0]);
    olv[1] = mfma16(pf[1], ones, olv[1]);
    __builtin_amdgcn_s_setprio(0);
  }

  // ---- main loop: branch-free ----
  for (int t = 1; t < 32; ++t) {
    bf16x8 vfr[8];
    const short* vt = vB + (size_t)t * 4096;
#pragma unroll
    for (int n = 0; n < 8; ++n)
      vfr[n] = *(const bf16x8*)(vt + n * 512 + lane * 8);

    f32x4 s0[2], s1[2];
    __builtin_amdgcn_s_setprio(1);
#pragma unroll
    for (int c = 0; c < 2; ++c) {
      s0[c] = mfma16(qf0, kf[c], zf);
      s1[c] = mfma16(qf1, kf[c], zf);
    }
    __builtin_amdgcn_s_setprio(0);

    if (t + 1 < 32) {
      const short* qt = qB + (size_t)(t + 1) * 1024;
      qf0 = *(const bf16x8*)(qt + lane * 8);
      qf1 = *(const bf16x8*)(qt + 512 + lane * 8);
    }

#pragma unroll
    for (int c = 0; c < 2; ++c) {
      float p[8];
#pragma unroll
      for (int r = 0; r < 4; ++r) {
        p[r]     = fast_exp2(s0[c][r] - ma[c]);
        p[4 + r] = fast_exp2(s1[c][r] - ma[c]);
      }
      union { bf16x8 v8; unsigned u[4]; } pk;
      pk.u[0] = cvt_pk_bf16(p[0], p[1]);
      pk.u[1] = cvt_pk_bf16(p[2], p[3]);
      pk.u[2] = cvt_pk_bf16(p[4], p[5]);
      pk.u[3] = cvt_pk_bf16(p[6], p[7]);
      pf[c] = pk.v8;
    }

    __builtin_amdgcn_s_setprio(1);
#pragma unroll
    for (int n = 0; n < 8; ++n) {
      o[0][n] = mfma16(pf[0], vfr[n], o[0][n]);
      o[1][n] = mfma16(pf[1], vfr[n], o[1][n]);
    }
    olv[0] = mfma16(pf[0], ones, olv[0]);
    olv[1] = mfma16(pf[1], ones, olv[1]);
    __builtin_amdgcn_s_setprio(0);
  }

  auto write_slot = [&](int s) {
#pragma unroll
    for (int c = 0; c < 2; ++c)
#pragma unroll
      for (int n = 0; n < 8; ++n)
        *(f32x4*)&OS[s][(c * 8 + n) * 256 + lane * 4] = o[c][n];
#pragma unroll
    for (int c = 0; c < 2; ++c)
      *(f32x4*)&OL[s][c * 256 + lane * 4] = olv[c];
    if (lane < 16) {
#pragma unroll
      for (int c = 0; c < 2; ++c) MS[s][c * 16 + lo] = ma[c];
    }
  };
  auto merge_slot = [&](int s) {
#pragma unroll
    for (int c = 0; c < 2; ++c) {
      float ms = MS[s][c * 16 + lo];
      float M = fmaxf(ma[c], ms);
      float eo = fast_exp2(ma[c] - M), es = fast_exp2(ms - M);
      ma[c] = M;
      float eor[4], esr[4];
#pragma unroll
      for (int r = 0; r < 4; ++r) {
        eor[r] = __shfl(eo, 4 * g + r, 64);
        esr[r] = __shfl(es, 4 * g + r, 64);
      }
#pragma unroll
      for (int n = 0; n < 8; ++n) {
        f32x4 v = *(f32x4*)&OS[s][(c * 8 + n) * 256 + lane * 4];
#pragma unroll
        for (int r = 0; r < 4; ++r)
          o[c][n][r] = eor[r] * o[c][n][r] + esr[r] * v[r];
      }
      f32x4 vl = *(f32x4*)&OL[s][c * 256 + lane * 4];
#pragma unroll
      for (int r = 0; r < 4; ++r)
        olv[c][r] = eor[r] * olv[c][r] + esr[r] * vl[r];
    }
  };

  if (wid == 1) write_slot(0);
  if (wid == 3) write_slot(1);
  __syncthreads();
  if (wid == 0) merge_slot(0);
  if (wid == 2) merge_slot(1);
  __syncthreads();
  if (wid == 2) write_slot(0);
  __syncthreads();
  if (wid == 0) {
    merge_slot(0);
    float* outp = out + (size_t)(b * SEQ + iw) * OUTC;
#pragma unroll
    for (int c = 0; c < 2; ++c) {
      float lir[4];
#pragma unroll
      for (int r = 0; r < 4; ++r) lir[r] = 1.f / olv[c][r];
#pragma unroll
      for (int n = 0; n < 8; ++n) {
        float bu = bias[n * 16 + lo];
#pragma unroll
        for (int r = 0; r < 4; ++r)
          outp[(size_t)(c * 16 + 4 * g + r) * OUTC + n * 16 + lo] =
              o[c][n][r] * lir[r] + bu;
      }
    }
  }
}

// ---------------------------------------------------------------------------
extern "C" void kernel_launch(void* const* d_in, const int* in_sizes, int n_in,
                              void* d_out, int out_size, void* d_ws, size_t ws_size,
                              hipStream_t stream) {
  (void)in_sizes; (void)n_in; (void)out_size; (void)ws_size;
  const float* x      = (const float*)d_in[0];
  const float* weight = (const float*)d_in[1];
  const float* bias   = (const float*)d_in[2];
  const float* wq     = (const float*)d_in[3];
  const float* bq     = (const float*)d_in[4];
  const float* wk     = (const float*)d_in[5];
  const float* bk     = (const float*)d_in[6];
  const float* wv     = (const float*)d_in[7];
  const float* bv     = (const float*)d_in[8];
  float* out = (float*)d_out;

  char* ws = (char*)d_ws;
  short* kbuf = (short*)(ws);                                   // 1 MiB [p][32]
  short* vfb  = (short*)(ws + ((size_t)1 << 20));               // 4 MiB VF tiles
  short* qlb  = (short*)(ws + ((size_t)5 << 20));               // 1 MiB QL tiles
  // wqb|wkb|wfT form one contiguous 48KB "wall" used by k_proj
  short* wqb  = (short*)(ws + ((size_t)6 << 20));               // 8 KiB
  short* wkb  = (short*)(ws + ((size_t)6 << 20) + 8192);        // 8 KiB
  short* wfT  = (short*)(ws + ((size_t)6 << 20) + 16384);       // 32 KiB
  float* bfu  = (float*)(ws + ((size_t)6 << 20) + 49152);       // 512 B

  hipLaunchKernelGGL(k_fuse, dim3(OUTC), dim3(CIN), 0, stream,
                     wq, wk, wv, weight, bv, wqb, wkb, wfT, bfu);
  hipLaunchKernelGGL(k_proj, dim3(NB * SEQ / 64), dim3(256), 0, stream,
                     x, bq, bk, wqb /* = wall */, bfu, qlb, kbuf, vfb);
  hipLaunchKernelGGL(k_attn, dim3(NB * SEQ / 32), dim3(256), 0, stream,
                     qlb, kbuf, vfb, bias, out);
}

// Round 20
// 48.559 us; speedup vs baseline: 1.0812x; 1.0173x over previous
//
#include <hip/hip_runtime.h>

#define NB   4
#define SEQ  4096
#define CIN  128
#define C4D  32
#define OUTC 128
#define LOG2E 1.44269504f

typedef __attribute__((ext_vector_type(8))) short bf16x8;
typedef __attribute__((ext_vector_type(4))) float f32x4;

__device__ __forceinline__ short f2bf(float f) {
  union { float f; unsigned u; } v; v.f = f;
  unsigned r = v.u + 0x7FFFu + ((v.u >> 16) & 1u);
  return (short)(r >> 16);
}

__device__ __forceinline__ unsigned cvt_pk_bf16(float lo, float hi) {
  unsigned r;
  asm("v_cvt_pk_bf16_f32 %0, %1, %2" : "=v"(r) : "v"(lo), "v"(hi));
  return r;
}

// native 2^x (v_exp_f32) — exp2f() without fast-math lowers to slow OCML.
__device__ __forceinline__ float fast_exp2(float x) {
  float r;
  asm("v_exp_f32 %0, %1" : "=v"(r) : "v"(x));
  return r;
}

__device__ __forceinline__ f32x4 mfma16(bf16x8 a, bf16x8 b, f32x4 c) {
  return __builtin_amdgcn_mfma_f32_16x16x32_bf16(a, b, c, 0, 0, 0);
}

// ---------------------------------------------------------------------------
// Kernel 1: fold value-path weights (unchanged).
// ---------------------------------------------------------------------------
__global__ void k_fuse(const float* __restrict__ wq, const float* __restrict__ wk,
                       const float* __restrict__ wv, const float* __restrict__ weight,
                       const float* __restrict__ bv,
                       short* __restrict__ wqb, short* __restrict__ wkb,
                       short* __restrict__ wfT, float* __restrict__ bfu) {
  int u = blockIdx.x, c = threadIdx.x;
  float a0 = 0.f, a1 = 0.f, a2 = 0.f, a3 = 0.f;
  for (int o = 0; o < OUTC; o += 4) {
    a0 += wv[(o + 0) * CIN + c] * weight[(o + 0) * OUTC + u];
    a1 += wv[(o + 1) * CIN + c] * weight[(o + 1) * OUTC + u];
    a2 += wv[(o + 2) * CIN + c] * weight[(o + 2) * OUTC + u];
    a3 += wv[(o + 3) * CIN + c] * weight[(o + 3) * OUTC + u];
  }
  wfT[u * CIN + c] = f2bf((a0 + a1) + (a2 + a3));
  if (u < C4D) {
    wqb[u * CIN + c] = f2bf(wq[u * CIN + c]);
    wkb[u * CIN + c] = f2bf(wk[u * CIN + c]);
  }
  if (c == 0) {
    float b0 = 0.f, b1 = 0.f;
    for (int o = 0; o < OUTC; o += 2) {
      b0 += bv[o] * weight[o * OUTC + u];
      b1 += bv[o + 1] * weight[(o + 1) * OUTC + u];
    }
    bfu[u] = b0 + b1;
  }
}

// ---------------------------------------------------------------------------
// Kernel 2: projections (R19 version: hoisted x loads + cvt_pk, LDS-swizzled
// weights, K pre-scaled by log2e).
// ---------------------------------------------------------------------------
__device__ __forceinline__ int wswz(int byte) {
  return byte ^ (((byte >> 8) & 7) << 4);
}

__global__ __launch_bounds__(256) void k_proj(
    const float* __restrict__ x, const float* __restrict__ bq, const float* __restrict__ bk,
    const short* __restrict__ wall, const float* __restrict__ bfu,
    short* __restrict__ ql, short* __restrict__ kb, short* __restrict__ vfb) {
  const int tid = threadIdx.x;
  const int wid = tid >> 6, lane = tid & 63;
  const int lo = lane & 15, g = lane >> 4;
  const int p0 = blockIdx.x * 64 + wid * 16;

  __shared__ __align__(16) short WL[24576];   // 48KB swizzled weights

  // hoisted x loads: 8 independent float4 loads, all in flight at once
  float4 xa[4], xb[4];
#pragma unroll
  for (int kk = 0; kk < 4; ++kk) {
    const float* xp = x + (size_t)(p0 + lo) * CIN + kk * 32 + g * 8;
    xa[kk] = *(const float4*)xp;
    xb[kk] = *(const float4*)(xp + 4);
  }

#pragma unroll
  for (int i = 0; i < 12; ++i) {
    bf16x8 v = *(const bf16x8*)(wall + i * 2048 + tid * 8);
    *(bf16x8*)((char*)WL + wswz((i * 2048 + tid * 8) * 2)) = v;
  }
  __syncthreads();

  auto wfrag = [&](int idx) -> bf16x8 {
    return *(const bf16x8*)((char*)WL + wswz(idx * 2));
  };

  bf16x8 af[4];
#pragma unroll
  for (int kk = 0; kk < 4; ++kk) {
    union { bf16x8 v8; unsigned u[4]; } pk;
    pk.u[0] = cvt_pk_bf16(xa[kk].x, xa[kk].y);
    pk.u[1] = cvt_pk_bf16(xa[kk].z, xa[kk].w);
    pk.u[2] = cvt_pk_bf16(xb[kk].x, xb[kk].y);
    pk.u[3] = cvt_pk_bf16(xb[kk].z, xb[kk].w);
    af[kk] = pk.v8;
  }

  f32x4 aq[2] = {}, ak[2] = {}, as_[8] = {};

#pragma unroll
  for (int kk = 0; kk < 4; ++kk) {
#pragma unroll
    for (int n = 0; n < 2; ++n) {
      bf16x8 bq_ = wfrag((n * 16 + lo) * CIN + kk * 32 + g * 8);
      aq[n] = mfma16(af[kk], bq_, aq[n]);
      bf16x8 bk_ = wfrag(4096 + (n * 16 + lo) * CIN + kk * 32 + g * 8);
      ak[n] = mfma16(af[kk], bk_, ak[n]);
    }
#pragma unroll
    for (int n = 0; n < 8; ++n) {
      bf16x8 bs = wfrag(8192 + (n * 16 + lo) * CIN + kk * 32 + g * 8);
      as_[n] = mfma16(af[kk], bs, as_[n]);
    }
  }

#pragma unroll
  for (int n = 0; n < 2; ++n) {
    float bqv = bq[n * 16 + lo], bkv = bk[n * 16 + lo];
    int u = n * 16 + lo;
#pragma unroll
    for (int r = 0; r < 4; ++r) {
      int p = p0 + 4 * g + r;
      int bb = p >> 12, s = p & (SEQ - 1);
      ql[(size_t)bb * (SEQ * 32) + (size_t)(s >> 5) * 1024 + ((s >> 4) & 1) * 512 +
         (u >> 3) * 128 + (s & 15) * 8 + (u & 7)] = f2bf(aq[n][r] + bqv);
      kb[(size_t)p * C4D + u] = f2bf((ak[n][r] + bkv) * LOG2E);
    }
  }
  {
    const int p = p0 + 4 * g;          // r = 0; r=0..3 contiguous in VF
    const int bb = p >> 12, s = p & (SEQ - 1);
#pragma unroll
    for (int n = 0; n < 8; ++n) {
      int u = n * 16 + lo;
      float bvv = bfu[u];
      uint2 w;
      w.x = cvt_pk_bf16(as_[n][0] + bvv, as_[n][1] + bvv);
      w.y = cvt_pk_bf16(as_[n][2] + bvv, as_[n][3] + bvv);
      *(uint2*)&vfb[(size_t)bb * (SEQ * 128) + (size_t)(s >> 5) * 4096 + (u >> 4) * 512 +
                    ((s >> 2) & 3) * 128 + (u & 15) * 8 + ((s >> 4) & 1) * 4] = w;
    }
  }
}

// ---------------------------------------------------------------------------
// Kernel 3 (Design III + relaxed reg budget + unroll-2 pipeline): wave = 32
// i-rows, 4 waves/block, j-split 4, 32 iters. Grid supplies only 2 waves/
// SIMD, so launch_bounds is (256,2) — the (256,3) cap was paying register
// pressure for an occupancy level never achieved. unroll 2 gives adjacent
// iterations independent transients so the scheduler can overlap tile t+1's
// loads/QK with tile t's softmax/PV. Frozen-max, l via ones-MFMA.
// ---------------------------------------------------------------------------
__global__ __launch_bounds__(256, 2) void k_attn(
    const short* __restrict__ ql, const short* __restrict__ kb,
    const short* __restrict__ vfb, const float* __restrict__ bias,
    float* __restrict__ out) {
  const int tid = threadIdx.x;
  const int wid = tid >> 6, lane = tid & 63;
  const int lo = lane & 15, g = lane >> 4;
  const int bid = blockIdx.x;
  const int xb = ((bid & 7) << 6) | (bid >> 3);   // 512 blocks, bijective
  const int b = xb >> 7;
  const int iw = (xb & 127) * 32;

  __shared__ float OS[2][4096];
  __shared__ float OL[2][512];
  __shared__ float MS[2][32];

  const short* qB = ql + (size_t)b * (SEQ * 32) + (size_t)wid * 32768;
  const short* vB = vfb + (size_t)b * (SEQ * 128) + (size_t)wid * 131072;

  bf16x8 kf[2];
#pragma unroll
  for (int c = 0; c < 2; ++c)
    kf[c] = *(const bf16x8*)(kb + (size_t)(b * SEQ + iw + 16 * c + lo) * C4D + g * 8);

  f32x4 o[2][8];
#pragma unroll
  for (int c = 0; c < 2; ++c)
#pragma unroll
    for (int n = 0; n < 8; ++n) o[c][n] = (f32x4){0.f, 0.f, 0.f, 0.f};
  f32x4 olv[2];
  olv[0] = (f32x4){0.f, 0.f, 0.f, 0.f};
  olv[1] = (f32x4){0.f, 0.f, 0.f, 0.f};

  float ma[2];
  const f32x4 zf = {0.f, 0.f, 0.f, 0.f};
  bf16x8 ones;
#pragma unroll
  for (int e = 0; e < 8; ++e) ones[e] = (short)0x3F80;   // bf16 1.0

  bf16x8 pf[2];

  // prologue: Q tile 0
  bf16x8 qf0 = *(const bf16x8*)(qB + lane * 8);
  bf16x8 qf1 = *(const bf16x8*)(qB + 512 + lane * 8);

  // ---- tile 0 (peeled): exact per-row max, then process ----
  {
    bf16x8 vfr[8];
#pragma unroll
    for (int n = 0; n < 8; ++n)
      vfr[n] = *(const bf16x8*)(vB + n * 512 + lane * 8);

    f32x4 s0[2], s1[2];
    __builtin_amdgcn_s_setprio(1);
#pragma unroll
    for (int c = 0; c < 2; ++c) {
      s0[c] = mfma16(qf0, kf[c], zf);
      s1[c] = mfma16(qf1, kf[c], zf);
    }
    __builtin_amdgcn_s_setprio(0);

    // Q prefetch for t=1
    qf0 = *(const bf16x8*)(qB + 1024 + lane * 8);
    qf1 = *(const bf16x8*)(qB + 1536 + lane * 8);

#pragma unroll
    for (int c = 0; c < 2; ++c) {
      float tm = fmaxf(fmaxf(fmaxf(s0[c][0], s0[c][1]), fmaxf(s0[c][2], s0[c][3])),
                       fmaxf(fmaxf(s1[c][0], s1[c][1]), fmaxf(s1[c][2], s1[c][3])));
      tm = fmaxf(tm, __shfl_xor(tm, 16, 64));
      tm = fmaxf(tm, __shfl_xor(tm, 32, 64));
      ma[c] = tm;                       // frozen for the whole pass
    }

#pragma unroll
    for (int c = 0; c < 2; ++c) {
      float p[8];
#pragma unroll
      for (int r = 0; r < 4; ++r) {
        p[r]     = fast_exp2(s0[c][r] - ma[c]);
        p[4 + r] = fast_exp2(s1[c][r] - ma[c]);
      }
      union { bf16x8 v8; unsigned u[4]; } pk;
      pk.u[0] = cvt_pk_bf16(p[0], p[1]);
      pk.u[1] = cvt_pk_bf16(p[2], p[3]);
      pk.u[2] = cvt_pk_bf16(p[4], p[5]);
      pk.u[3] = cvt_pk_bf16(p[6], p[7]);
      pf[c] = pk.v8;
    }

    __builtin_amdgcn_s_setprio(1);
#pragma unroll
    for (int n = 0; n < 8; ++n) {
      o[0][n] = mfma16(pf[0], vfr[n], o[0][n]);
      o[1][n] = mfma16(pf[1], vfr[n], o[1][n]);
    }
    olv[0] = mfma16(pf[0], ones, olv[0]);
    olv[1] = mfma16(pf[1], ones, olv[1]);
    __builtin_amdgcn_s_setprio(0);
  }

  // ---- main loop: branch-free, unroll 2 for cross-iteration ILP ----
#pragma unroll 2
  for (int t = 1; t < 32; ++t) {
    bf16x8 vfr[8];
    const short* vt = vB + (size_t)t * 4096;
#pragma unroll
    for (int n = 0; n < 8; ++n)
      vfr[n] = *(const bf16x8*)(vt + n * 512 + lane * 8);

    f32x4 s0[2], s1[2];
    __builtin_amdgcn_s_setprio(1);
#pragma unroll
    for (int c = 0; c < 2; ++c) {
      s0[c] = mfma16(qf0, kf[c], zf);
      s1[c] = mfma16(qf1, kf[c], zf);
    }
    __builtin_amdgcn_s_setprio(0);

    if (t + 1 < 32) {
      const short* qt = qB + (size_t)(t + 1) * 1024;
      qf0 = *(const bf16x8*)(qt + lane * 8);
      qf1 = *(const bf16x8*)(qt + 512 + lane * 8);
    }

#pragma unroll
    for (int c = 0; c < 2; ++c) {
      float p[8];
#pragma unroll
      for (int r = 0; r < 4; ++r) {
        p[r]     = fast_exp2(s0[c][r] - ma[c]);
        p[4 + r] = fast_exp2(s1[c][r] - ma[c]);
      }
      union { bf16x8 v8; unsigned u[4]; } pk;
      pk.u[0] = cvt_pk_bf16(p[0], p[1]);
      pk.u[1] = cvt_pk_bf16(p[2], p[3]);
      pk.u[2] = cvt_pk_bf16(p[4], p[5]);
      pk.u[3] = cvt_pk_bf16(p[6], p[7]);
      pf[c] = pk.v8;
    }

    __builtin_amdgcn_s_setprio(1);
#pragma unroll
    for (int n = 0; n < 8; ++n) {
      o[0][n] = mfma16(pf[0], vfr[n], o[0][n]);
      o[1][n] = mfma16(pf[1], vfr[n], o[1][n]);
    }
    olv[0] = mfma16(pf[0], ones, olv[0]);
    olv[1] = mfma16(pf[1], ones, olv[1]);
    __builtin_amdgcn_s_setprio(0);
  }

  auto write_slot = [&](int s) {
#pragma unroll
    for (int c = 0; c < 2; ++c)
#pragma unroll
      for (int n = 0; n < 8; ++n)
        *(f32x4*)&OS[s][(c * 8 + n) * 256 + lane * 4] = o[c][n];
#pragma unroll
    for (int c = 0; c < 2; ++c)
      *(f32x4*)&OL[s][c * 256 + lane * 4] = olv[c];
    if (lane < 16) {
#pragma unroll
      for (int c = 0; c < 2; ++c) MS[s][c * 16 + lo] = ma[c];
    }
  };
  auto merge_slot = [&](int s) {
#pragma unroll
    for (int c = 0; c < 2; ++c) {
      float ms = MS[s][c * 16 + lo];
      float M = fmaxf(ma[c], ms);
      float eo = fast_exp2(ma[c] - M), es = fast_exp2(ms - M);
      ma[c] = M;
      float eor[4], esr[4];
#pragma unroll
      for (int r = 0; r < 4; ++r) {
        eor[r] = __shfl(eo, 4 * g + r, 64);
        esr[r] = __shfl(es, 4 * g + r, 64);
      }
#pragma unroll
      for (int n = 0; n < 8; ++n) {
        f32x4 v = *(f32x4*)&OS[s][(c * 8 + n) * 256 + lane * 4];
#pragma unroll
        for (int r = 0; r < 4; ++r)
          o[c][n][r] = eor[r] * o[c][n][r] + esr[r] * v[r];
      }
      f32x4 vl = *(f32x4*)&OL[s][c * 256 + lane * 4];
#pragma unroll
      for (int r = 0; r < 4; ++r)
        olv[c][r] = eor[r] * olv[c][r] + esr[r] * vl[r];
    }
  };

  if (wid == 1) write_slot(0);
  if (wid == 3) write_slot(1);
  __syncthreads();
  if (wid == 0) merge_slot(0);
  if (wid == 2) merge_slot(1);
  __syncthreads();
  if (wid == 2) write_slot(0);
  __syncthreads();
  if (wid == 0) {
    merge_slot(0);
    float* outp = out + (size_t)(b * SEQ + iw) * OUTC;
#pragma unroll
    for (int c = 0; c < 2; ++c) {
      float lir[4];
#pragma unroll
      for (int r = 0; r < 4; ++r) lir[r] = 1.f / olv[c][r];
#pragma unroll
      for (int n = 0; n < 8; ++n) {
        float bu = bias[n * 16 + lo];
#pragma unroll
        for (int r = 0; r < 4; ++r)
          outp[(size_t)(c * 16 + 4 * g + r) * OUTC + n * 16 + lo] =
              o[c][n][r] * lir[r] + bu;
      }
    }
  }
}

// ---------------------------------------------------------------------------
extern "C" void kernel_launch(void* const* d_in, const int* in_sizes, int n_in,
                              void* d_out, int out_size, void* d_ws, size_t ws_size,
                              hipStream_t stream) {
  (void)in_sizes; (void)n_in; (void)out_size; (void)ws_size;
  const float* x      = (const float*)d_in[0];
  const float* weight = (const float*)d_in[1];
  const float* bias   = (const float*)d_in[2];
  const float* wq     = (const float*)d_in[3];
  const float* bq     = (const float*)d_in[4];
  const float* wk     = (const float*)d_in[5];
  const float* bk     = (const float*)d_in[6];
  const float* wv     = (const float*)d_in[7];
  const float* bv     = (const float*)d_in[8];
  float* out = (float*)d_out;

  char* ws = (char*)d_ws;
  short* kbuf = (short*)(ws);                                   // 1 MiB [p][32]
  short* vfb  = (short*)(ws + ((size_t)1 << 20));               // 4 MiB VF tiles
  short* qlb  = (short*)(ws + ((size_t)5 << 20));               // 1 MiB QL tiles
  // wqb|wkb|wfT form one contiguous 48KB "wall" used by k_proj
  short* wqb  = (short*)(ws + ((size_t)6 << 20));               // 8 KiB
  short* wkb  = (short*)(ws + ((size_t)6 << 20) + 8192);        // 8 KiB
  short* wfT  = (short*)(ws + ((size_t)6 << 20) + 16384);       // 32 KiB
  float* bfu  = (float*)(ws + ((size_t)6 << 20) + 49152);       // 512 B

  hipLaunchKernelGGL(k_fuse, dim3(OUTC), dim3(CIN), 0, stream,
                     wq, wk, wv, weight, bv, wqb, wkb, wfT, bfu);
  hipLaunchKernelGGL(k_proj, dim3(NB * SEQ / 64), dim3(256), 0, stream,
                     x, bq, bk, wqb /* = wall */, bfu, qlb, kbuf, vfb);
  hipLaunchKernelGGL(k_attn, dim3(NB * SEQ / 32), dim3(256), 0, stream,
                     qlb, kbuf, vfb, bias, out);
}